// Round 1
// baseline (128.850 us; speedup 1.0000x reference)
//
#include <hip/hip_runtime.h>
#include <math.h>

#define NS 2000
#define EPS_F 1.1920928955078125e-07f
#define CH 32
#define BLOCK 512
#define WPB (BLOCK / 64)

// Kernel 1: grid-dependent tables (atanh(x), 1/(1-x^2)), computed once.
// Grid replicates numpy linspace: f64 arange*step + start, cast to f32,
// endpoint set exactly.
__global__ void build_table(float2* __restrict__ tab) {
    int i = blockIdx.x * blockDim.x + threadIdx.x;
    if (i >= NS) return;
    const double y0 = -0.9999, y1 = 0.9999;
    const double step = (y1 - y0) / 1999.0;
    float x = (i == NS - 1) ? (float)y1 : (float)(y0 + (double)i * step);
    float ratio = (1.0f + x) / (1.0f - x) + EPS_F;   // ref: (1+x)/(1-x) + EPS
    float a = 0.5f * logf(ratio);                    // atanh_x
    float w = 1.0f / (1.0f - x * x);                 // 1/(1-x^2)
    tab[i] = make_float2(a, w);
}

// Kernel 2: one wave per (batch, action) element.
// Lane l owns contiguous grid chunk [32l, 32l+32): sequential per-lane cumsum
// matches the reference's cumsum ordering; wave scan stitches lane offsets.
// LDS slots XOR-swizzled so the stride-32-entry chunked read is conflict-free.
__global__ __launch_bounds__(BLOCK) void sample_kernel(
    const float* __restrict__ mean, const float* __restrict__ stdv,
    const float* __restrict__ uni, const float2* __restrict__ gtab,
    float* __restrict__ out_vals, float* __restrict__ out_probs, int nElem) {
    __shared__ float2 tab[2048];
    for (int i = threadIdx.x; i < NS; i += BLOCK) {
        int s = i ^ ((i >> 5) & 15);
        tab[s] = gtab[i];
    }
    __syncthreads();

    const int lane = threadIdx.x & 63;
    const int wid = threadIdx.x >> 6;
    const int elem = blockIdx.x * WPB + wid;
    if (elem >= nElem) return;

    const float mu = mean[elem];
    const float sg = stdv[elem] + EPS_F;            // ref: std + EPS
    const float u = uni[elem];
    const float sg2 = sg * sg;
    const float nden = -2.0f * sg2;                 // ref: -2.0 * sg**2
    const float rden = 1.0f / nden;                 // per-element precise div
    const float normc = 1.0f / sqrtf(6.2831853071795864f * sg2);  // 1/sqrt(2*pi*sg^2)

    const int base = lane * CH;
    float p[CH];
    float s = 0.0f;

    // Pass 1: raw probs into registers + per-lane sequential partial sum.
    #pragma unroll
    for (int k = 0; k < CH; k++) {
        int i = base + k;
        int ic = (i < NS) ? i : (NS - 1);
        int slot = ic ^ ((ic >> 5) & 15);
        float2 aw = tab[slot];
        float d = aw.x - mu;
        float lt = (d * d) * rden;                  // (atanh_x - mu)^2 / (-2 sg^2)
        float e = __expf(lt);                       // lt <= 0 always, e in [0,1]
        float pk = (aw.y * normc) * e;              // (1/(1-x^2)) * (1/sqrt(..)) * exp
        pk = (i < NS) ? pk : 0.0f;
        p[k] = pk;
        s += pk;
    }

    // Inclusive wave scan of lane sums -> exclusive offset + total S.
    float incl = s;
    #pragma unroll
    for (int o = 1; o < 64; o <<= 1) {
        float t2 = __shfl_up(incl, o, 64);
        if (lane >= o) incl += t2;
    }
    const float S = __shfl(incl, 63, 64);
    const float denom = S + EPS_F;                  // ref: sum + EPS
    const float t = u * denom;                      // rawcum > u*(S+EPS)  <=>  cdf > u

    // Pass 2: sequential cumsum + first-crossing selection (branchless).
    float run = incl - s;                           // exclusive lane offset
    int cand = 0x7fffffff;
    float pc = 0.0f;
    #pragma unroll
    for (int k = 0; k < CH; k++) {
        run += p[k];
        bool c = (run > t) && ((base + k) < NS) && (cand == 0x7fffffff);
        if (c) { cand = base + k; pc = p[k]; }
    }

    // Wave min-reduce of candidate indices.
    int mn = cand;
    #pragma unroll
    for (int o = 1; o < 64; o <<= 1) {
        int other = __shfl_xor(mn, o, 64);
        mn = min(mn, other);
    }

    bool writer;
    int idx;
    float psel;
    if (mn == 0x7fffffff) {                         // no crossing: argmax of all-False = 0
        writer = (lane == 0);
        idx = 0;
        psel = p[0];
    } else {
        writer = (cand == mn);                      // exactly one lane matches
        idx = mn;
        psel = pc;
    }
    if (writer) {
        const double y0 = -0.9999, y1 = 0.9999;
        const double step = (y1 - y0) / 1999.0;
        float gv = (idx == NS - 1) ? (float)y1 : (float)(y0 + (double)idx * step);
        out_vals[elem] = gv;
        out_probs[elem] = psel / denom;             // ref: probs / (sum + EPS)
    }
}

extern "C" void kernel_launch(void* const* d_in, const int* in_sizes, int n_in,
                              void* d_out, int out_size, void* d_ws, size_t ws_size,
                              hipStream_t stream) {
    const float* mean = (const float*)d_in[0];
    const float* stdv = (const float*)d_in[1];
    const float* uni = (const float*)d_in[2];
    float* out = (float*)d_out;
    const int nElem = in_sizes[0];                  // 4096*16 = 65536
    float* out_vals = out;                          // first output, flat
    float* out_probs = out + nElem;                 // second output, flat
    float2* tab = (float2*)d_ws;                    // 2000 * 8B = 16 KB scratch

    build_table<<<(NS + 255) / 256, 256, 0, stream>>>(tab);

    const int grid = (nElem + WPB - 1) / WPB;
    sample_kernel<<<grid, BLOCK, 0, stream>>>(mean, stdv, uni, tab,
                                              out_vals, out_probs, nElem);
}

// Round 3
// 101.194 us; speedup vs baseline: 1.2733x; 1.2733x over previous
//
#include <hip/hip_runtime.h>
#include <math.h>

#define NS 2000
#define NPAD 2048
#define EPS_F 1.1920928955078125e-07f
#define CH 32
#define BLOCK 512
#define WPB (BLOCK / 64)
#define LOG2E 1.4426950408889634f

// 2^x via the hardware instruction (v_exp_f32). Named wrapper because
// __exp2f collides with glibc's math.h host prototype.
__device__ __forceinline__ float exp2_hw(float x) {
    return __builtin_amdgcn_exp2f(x);
}

// Kernel 1: build padded, TRANSPOSED tables in workspace.
//   original grid index i  ->  slot (i%32)*64 + i/32
// so that lane l, step k reads slot k*64+l (stride-1 across lanes -> 2-way
// bank alias only, and LDS address folds to base + k*256 immediate).
// Entries i >= NS are padded with w=0 (contribute zero probability).
__global__ void build_table(float* __restrict__ tabA, float* __restrict__ tabW) {
    int i = blockIdx.x * blockDim.x + threadIdx.x;
    if (i >= NPAD) return;
    float a = 0.0f, w = 0.0f;
    if (i < NS) {
        const double y0 = -0.9999, y1 = 0.9999;
        const double step = (y1 - y0) / 1999.0;
        float x = (i == NS - 1) ? (float)y1 : (float)(y0 + (double)i * step);
        float ratio = (1.0f + x) / (1.0f - x) + EPS_F;  // ref: (1+x)/(1-x)+EPS
        a = 0.5f * logf(ratio);                         // atanh_x
        w = 1.0f / (1.0f - x * x);                      // 1/(1-x^2)
    }
    int slot = (i & 31) * 64 + (i >> 5);
    tabA[slot] = a;
    tabW[slot] = w;
}

// Kernel 2: one wave per (batch, action) element. Lane l owns grid chunk
// [32l, 32l+32). Selection index = count of cumsum entries <= t (cumsum is
// monotone since all probs >= 0), so pass 2 is add+cmp+addc per point.
__global__ __launch_bounds__(BLOCK) void sample_kernel(
    const float* __restrict__ mean, const float* __restrict__ stdv,
    const float* __restrict__ uni, const float* __restrict__ gA,
    const float* __restrict__ gW,
    float* __restrict__ out_vals, float* __restrict__ out_probs, int nElem) {
    __shared__ float sA[NPAD];
    __shared__ float sW[NPAD];
    for (int j = threadIdx.x; j < NPAD; j += BLOCK) {
        sA[j] = gA[j];
        sW[j] = gW[j];
    }
    __syncthreads();

    const int lane = threadIdx.x & 63;
    const int wid = threadIdx.x >> 6;
    const int elem = blockIdx.x * WPB + wid;
    if (elem >= nElem) return;

    const float mu = mean[elem];
    const float sg = stdv[elem] + EPS_F;               // ref: std + EPS
    const float u = uni[elem];
    const float sg2 = sg * sg;
    const float rden2 = LOG2E / (-2.0f * sg2);         // fold log2e: exp(x)=exp2(x*log2e)
    const float normc = 1.0f / sqrtf(6.2831853071795864f * sg2);

    // Pass 1: q_k = w * exp2((a-mu)^2 * rden2)  (normc factored out; rescale t)
    float q[CH];
    float s = 0.0f;
    #pragma unroll
    for (int k = 0; k < CH; k++) {
        float a = sA[k * 64 + lane];                   // ds_read_b32 offset:k*256
        float w = sW[k * 64 + lane];
        float d = a - mu;
        float e = exp2_hw((d * d) * rden2);            // lt <= 0 always
        float qk = w * e;
        q[k] = qk;
        s += qk;
    }

    // Inclusive wave scan of lane sums -> total S and exclusive lane offset.
    float incl = s;
    #pragma unroll
    for (int o = 1; o < 64; o <<= 1) {
        float t2 = __shfl_up(incl, o, 64);
        if (lane >= o) incl += t2;
    }
    const float S = __shfl(incl, 63, 64);              // wave-uniform q-sum
    const float denom = S * normc + EPS_F;             // ref: sum(probs) + EPS
    const float tt = (u * denom) / normc;              // threshold in q-space

    // Pass 2: idx = #{ j : cumsum_q_j <= tt }  (monotone cumsum, t uniform)
    float run = incl - s;                              // exclusive lane offset
    int cnt = 0;
    #pragma unroll
    for (int k = 0; k < CH; k++) {
        run += q[k];
        cnt += (run <= tt) ? 1 : 0;
    }
    #pragma unroll
    for (int o = 1; o < 64; o <<= 1) {
        cnt += __shfl_xor(cnt, o, 64);
    }
    // cnt is now wave-uniform total. Reachable values: [0,1999] or 2048
    // (padded entries can only be counted if ALL entries are). 2048 = no
    // crossing -> reference argmax(all False) = 0.
    int idx = (cnt >= NS) ? 0 : cnt;

    if (lane == 0) {
        int slot = (idx & 31) * 64 + (idx >> 5);
        float a = sA[slot];
        float w = sW[slot];
        float d = a - mu;
        float pk = w * exp2_hw((d * d) * rden2) * normc;  // raw prob at idx
        const double y0 = -0.9999, y1 = 0.9999;
        const double step = (y1 - y0) / 1999.0;
        float gv = (idx == NS - 1) ? (float)y1 : (float)(y0 + (double)idx * step);
        out_vals[elem] = gv;
        out_probs[elem] = pk / denom;                  // ref: probs/(sum+EPS)
    }
}

extern "C" void kernel_launch(void* const* d_in, const int* in_sizes, int n_in,
                              void* d_out, int out_size, void* d_ws, size_t ws_size,
                              hipStream_t stream) {
    const float* mean = (const float*)d_in[0];
    const float* stdv = (const float*)d_in[1];
    const float* uni = (const float*)d_in[2];
    float* out = (float*)d_out;
    const int nElem = in_sizes[0];                     // 4096*16 = 65536
    float* out_vals = out;
    float* out_probs = out + nElem;
    float* tabA = (float*)d_ws;                        // 2048 f32
    float* tabW = tabA + NPAD;                         // 2048 f32

    build_table<<<NPAD / 256, 256, 0, stream>>>(tabA, tabW);

    const int grid = (nElem + WPB - 1) / WPB;
    sample_kernel<<<grid, BLOCK, 0, stream>>>(mean, stdv, uni, tabA, tabW,
                                              out_vals, out_probs, nElem);
}

// Round 4
// 91.445 us; speedup vs baseline: 1.4090x; 1.1066x over previous
//
#include <hip/hip_runtime.h>
#include <math.h>

#define NS 2000
#define NPAD 2048
#define EPS_F 1.1920928955078125e-07f
#define BLOCK 1024
#define WPB (BLOCK / 64)          // 16 elements (waves) per block
#define LOG2E 1.4426950408889634f

// 2^x via v_exp_f32 (named wrapper: __exp2f collides with glibc math.h).
__device__ __forceinline__ float exp2_hw(float x) {
    return __builtin_amdgcn_exp2f(x);
}

// Kernel 1: build two table views in workspace.
//   tabT: transposed pairs. float4 slot (kk*64 + l) holds points 32l+2kk and
//         32l+2kk+1 as (a0, lw0, a1, lw1) -> pass-1 lane-consecutive b128.
//   tab2: linear float2 (a, lw) -> cooperative chunk recompute + epilogue.
// a = atanh-table value, lw = log2(1/(1-x^2)); pads get lw=-1000 => q=0.
__global__ void build_table(float2* __restrict__ tabT, float2* __restrict__ tab2) {
    int i = blockIdx.x * blockDim.x + threadIdx.x;
    if (i >= NPAD) return;
    float a = 0.0f, lw = -1000.0f;
    if (i < NS) {
        const double y0 = -0.9999, y1 = 0.9999;
        const double step = (y1 - y0) / 1999.0;
        float x = (i == NS - 1) ? (float)y1 : (float)(y0 + (double)i * step);
        float ratio = (1.0f + x) / (1.0f - x) + EPS_F;   // ref: (1+x)/(1-x)+EPS
        a = 0.5f * logf(ratio);                          // atanh_x
        float w = 1.0f / (1.0f - x * x);                 // 1/(1-x^2), >= 1
        lw = log2f(w);
    }
    tab2[i] = make_float2(a, lw);
    int l = i >> 5, k = i & 31, kk = k >> 1, h = k & 1;
    tabT[(kk * 64 + l) * 2 + h] = make_float2(a, lw);
}

// Kernel 2: one wave per element. Lane l owns grid chunk [32l, 32l+32).
// Pass 1 accumulates only the per-lane sum (no q[] array -> nothing for the
// compiler to rematerialize). Selection is hierarchical: wave scan -> ballot
// picks the crossing lane; 64 lanes cooperatively re-evaluate that single
// 32-point chunk; ballot picks the point.
__global__ __launch_bounds__(BLOCK) void sample_kernel(
    const float* __restrict__ mean, const float* __restrict__ stdv,
    const float* __restrict__ uni, const float4* __restrict__ gT,
    const float4* __restrict__ gP,
    float* __restrict__ out_vals, float* __restrict__ out_probs, int nElem) {
    __shared__ float4 sT[NPAD / 2];     // transposed pair view (16 KB)
    __shared__ float4 sPbuf[NPAD / 2];  // linear view (16 KB)
    float2* sP = (float2*)sPbuf;
    {
        int t = threadIdx.x;            // 0..1023 == NPAD/2-1
        sT[t] = gT[t];
        sPbuf[t] = gP[t];
    }
    __syncthreads();

    const int lane = threadIdx.x & 63;
    const int wid = threadIdx.x >> 6;
    const int elem = blockIdx.x * WPB + wid;
    if (elem >= nElem) return;

    const float mu = mean[elem];
    const float sg = stdv[elem] + EPS_F;               // ref: std + EPS
    const float u = uni[elem];
    const float sg2 = sg * sg;
    const float rden2 = LOG2E / (-2.0f * sg2);         // exp(x)=exp2(x*log2e)
    const float normc = 1.0f / sqrtf(6.2831853071795864f * sg2);

    // Pass 1: per-lane sum of q_i = exp2((a-mu)^2*rden2 + lw), index order.
    float s = 0.0f;
    #pragma unroll
    for (int kk = 0; kk < 16; kk++) {
        float4 v = sT[kk * 64 + lane];                 // 2 points, b128
        float d0 = v.x - mu;
        s += exp2_hw(fmaf(d0 * d0, rden2, v.y));
        float d1 = v.z - mu;
        s += exp2_hw(fmaf(d1 * d1, rden2, v.w));
    }

    // Inclusive wave scan of lane sums.
    float incl = s;
    #pragma unroll
    for (int o = 1; o < 64; o <<= 1) {
        float t2 = __shfl_up(incl, o, 64);
        if (lane >= o) incl += t2;
    }
    const float S = __shfl(incl, 63, 64);              // wave-uniform q-sum
    const float denom = S * normc + EPS_F;             // ref: sum(probs)+EPS
    const float tt = (u * denom) / normc;              // threshold in q-space

    // Crossing lane: first lane whose inclusive sum exceeds tt.
    unsigned long long mgt = __ballot(incl > tt);
    int jstar = mgt ? __builtin_ctzll(mgt) : 64;

    // Cooperative re-eval of chunk jstar (one point per lane, both halves
    // duplicate). Linear table -> broadcast/2-way LDS access, conflict-free.
    int jj = (jstar < 64) ? jstar : 0;
    float exclb = __shfl(incl - s, jj, 64);            // exclusive offset
    int c = lane & 31;
    float2 al = sP[jj * 32 + c];
    float d = al.x - mu;
    float qc = exp2_hw(fmaf(d * d, rden2, al.y));
    float cum = qc;
    #pragma unroll
    for (int o = 1; o < 32; o <<= 1) {
        float t2 = __shfl_up(cum, o, 32);
        if (c >= o) cum += t2;
    }
    cum += exclb;
    unsigned int m2 = (unsigned int)(__ballot(cum > tt) & 0xffffffffULL);
    int sub = m2 ? (int)__builtin_ctz(m2) : 32;
    int idx = (jstar >= 64) ? 0 : min(jstar * 32 + sub, NS - 1);

    if (lane == 0) {
        float2 al2 = sP[idx];
        float dd = al2.x - mu;
        float pk = exp2_hw(fmaf(dd * dd, rden2, al2.y)) * normc;
        const double y0 = -0.9999, y1 = 0.9999;
        const double step = (y1 - y0) / 1999.0;
        float gv = (idx == NS - 1) ? (float)y1 : (float)(y0 + (double)idx * step);
        out_vals[elem] = gv;
        out_probs[elem] = pk / denom;                  // ref: probs/(sum+EPS)
    }
}

extern "C" void kernel_launch(void* const* d_in, const int* in_sizes, int n_in,
                              void* d_out, int out_size, void* d_ws, size_t ws_size,
                              hipStream_t stream) {
    const float* mean = (const float*)d_in[0];
    const float* stdv = (const float*)d_in[1];
    const float* uni = (const float*)d_in[2];
    float* out = (float*)d_out;
    const int nElem = in_sizes[0];                     // 4096*16 = 65536
    float* out_vals = out;
    float* out_probs = out + nElem;

    float2* tabT = (float2*)d_ws;                      // 2048 float2 = 16 KB
    float2* tab2 = tabT + NPAD;                        // 2048 float2 = 16 KB

    build_table<<<NPAD / 256, 256, 0, stream>>>(tabT, tab2);

    const int grid = (nElem + WPB - 1) / WPB;
    sample_kernel<<<grid, BLOCK, 0, stream>>>(mean, stdv, uni,
                                              (const float4*)tabT,
                                              (const float4*)tab2,
                                              out_vals, out_probs, nElem);
}